// Round 12
// baseline (129.183 us; speedup 1.0000x reference)
//
#include <hip/hip_runtime.h>
#include <math.h>

#define M_ROWS 8192   // B*S
#define KDIM   8192   // V
#define NDIM   512    // D
#define RCAP   512    // glist slots per row (mean nnz 82, sigma 9)

typedef float    f32x4  __attribute__((ext_vector_type(4)));
typedef unsigned u32x4  __attribute__((ext_vector_type(4)));
typedef __bf16   bf16x8 __attribute__((ext_vector_type(8)));

// d_ws: [0,8M) WT bf16[8192][512] | [8M,24M) glist u32[8192][512]
//       [24M,+128K) count4 u32x4[8192] (cumulative quarter cuts | sentinel)
#define WS_GLIST  (8u  * 1024 * 1024)
#define WS_COUNT  (24u * 1024 * 1024)

// ---------------------------------------------------------------------------
// K1: W [512,8192] f32 -> WT [8192,512] bf16 (proven R6/R7).
__global__ __launch_bounds__(256)
void transpose_w(const float* __restrict__ W, __bf16* __restrict__ WT) {
  __shared__ float tile[64][65];
  const int t  = threadIdx.x;
  const int v0 = (blockIdx.x & 127) << 6;
  const int d0 = (blockIdx.x >> 7) << 6;
  #pragma unroll
  for (int i = 0; i < 4; ++i) {
    int idx = i * 256 + t;
    int r = idx >> 4, c = (idx & 15) << 2;
    f32x4 val = *(const f32x4*)(W + (size_t)(d0 + r) * KDIM + v0 + c);
    tile[r][c + 0] = val.x; tile[r][c + 1] = val.y;
    tile[r][c + 2] = val.z; tile[r][c + 3] = val.w;
  }
  __syncthreads();
  #pragma unroll
  for (int i = 0; i < 2; ++i) {
    int idx = i * 256 + t;
    int vr = idx >> 3, d8 = (idx & 7) << 3;
    bf16x8 u;
    #pragma unroll
    for (int j = 0; j < 8; ++j) u[j] = (__bf16)tile[d8 + j][vr];
    *(bf16x8*)(WT + (size_t)(v0 + vr) * NDIM + d0 + d8) = u;
  }
}

// ---------------------------------------------------------------------------
// K2: pure scan+compact at HBM rate (proven R7). Quarter-cumulative cuts at
// pos 7/15/23 so gather launches can segment by v-quarter.
__global__ __launch_bounds__(256)
void scan_compact(const float* __restrict__ A, unsigned* __restrict__ glist,
                  u32x4* __restrict__ count4) {
  const int lane = threadIdx.x & 63;
  const int m    = blockIdx.x * 4 + (threadIdx.x >> 6);
  const float* arow = A + (size_t)m * KDIM;
  unsigned* rl = glist + (size_t)m * RCAP;

  const unsigned long long ltmask = (1ull << lane) - 1ull;
  unsigned cur = 0, cq0 = 0, cq1 = 0, cq2 = 0;
  bool ovf = false;

  f32x4 bufs[4];
  #pragma unroll
  for (int p = 0; p < 4; ++p)
    bufs[p] = __builtin_nontemporal_load((const f32x4*)(arow + p * 256 + lane * 4));

  #pragma unroll 4
  for (int pos = 0; pos < 32; ++pos) {
    f32x4 av = bufs[pos & 3];
    if (pos + 4 < 32)
      bufs[pos & 3] = __builtin_nontemporal_load(
          (const f32x4*)(arow + (pos + 4) * 256 + lane * 4));
    #pragma unroll
    for (int j = 0; j < 4; ++j) {
      unsigned long long msk = __ballot(av[j] != 0.0f);
      if (msk == 0) continue;
      unsigned cnt = (unsigned)__popcll(msk);
      if (cur + cnt <= RCAP) {
        if (av[j] != 0.0f) {
          unsigned pre = (unsigned)__popcll(msk & ltmask);
          unsigned fb  = (__float_as_uint(av[j]) + 0x8000u) & 0xFFFF0000u;
          rl[cur + pre] = fb | (unsigned)(pos * 256 + lane * 4 + j);
        }
        cur += cnt;
      } else {
        ovf = true;   // statistically unreachable at ~1% density
      }
    }
    if (pos == 7)  cq0 = cur;
    if (pos == 15) cq1 = cur;
    if (pos == 23) cq2 = cur;
  }
  if (lane == 0) {
    u32x4 c;
    c.x = ovf ? 0xFFFFFFFFu : cq0;
    c.y = cq1; c.z = cq2; c.w = cur;
    count4[m] = c;
  }
}

// ---------------------------------------------------------------------------
// K3 (x4 launches, qtr=0..3): gather ONE 2 MB v-quarter of WT for every row.
// The launch boundary grid-aligns the whole device on one quarter -> per-XCD
// live WT set = 2 MB < 4 MB L2 -> gathers served on-XCD (bypass fabric).
// fp32 C partials carried across launches (qtr0 writes, 1..2 RMW, 3 RMW+tanh).
// nt on A/C-partials/list so WT owns the L2. Sentinel -> exact re-scan in q3.
__global__ __launch_bounds__(256, 8)
void gather_qtr(const float* __restrict__ A, const __bf16* __restrict__ WT,
                const unsigned* __restrict__ glist,
                const u32x4* __restrict__ count4,
                float* __restrict__ C, int qtr) {
  const int lane = threadIdx.x & 63;
  const int m    = blockIdx.x * 4 + (threadIdx.x >> 6);
  const char* wtb = (const char*)WT;
  const unsigned* rl = glist + (size_t)m * RCAP;
  float* crow = C + (size_t)m * NDIM + lane * 8;

  float a0, a1, a2, a3, a4, a5, a6, a7;

#define FMA8(f, q)                                                          \
  {                                                                         \
    a0 = fmaf(f, __uint_as_float((q).x << 16), a0);                         \
    a1 = fmaf(f, __uint_as_float((q).x & 0xffff0000u), a1);                 \
    a2 = fmaf(f, __uint_as_float((q).y << 16), a2);                         \
    a3 = fmaf(f, __uint_as_float((q).y & 0xffff0000u), a3);                 \
    a4 = fmaf(f, __uint_as_float((q).z << 16), a4);                         \
    a5 = fmaf(f, __uint_as_float((q).z & 0xffff0000u), a5);                 \
    a6 = fmaf(f, __uint_as_float((q).w << 16), a6);                         \
    a7 = fmaf(f, __uint_as_float((q).w & 0xffff0000u), a7);                 \
  }

  const u32x4 cq = count4[m];
  if (cq.x == 0xFFFFFFFFu) {
    if (qtr < 3) return;               // exact fallback entirely in qtr 3
    a0 = a1 = a2 = a3 = a4 = a5 = a6 = a7 = 0.f;
    const float* arow = A + (size_t)m * KDIM;
    for (int it = 0; it < KDIM / 256; ++it) {
      f32x4 av = *(const f32x4*)(arow + it * 256 + lane * 4);
      #pragma unroll
      for (int j = 0; j < 4; ++j) {
        unsigned long long msk = __ballot(av[j] != 0.0f);
        while (msk) {
          int s = __builtin_ctzll(msk); msk &= msk - 1;
          float f = __shfl(av[j], s, 64);
          int v = it * 256 + s * 4 + j;
          u32x4 q = *(const u32x4*)(wtb + (size_t)v * (NDIM * 2) + lane * 16);
          FMA8(f, q);
        }
      }
    }
    f32x4 o0 = {tanhf(a0), tanhf(a1), tanhf(a2), tanhf(a3)};
    f32x4 o1 = {tanhf(a4), tanhf(a5), tanhf(a6), tanhf(a7)};
    __builtin_nontemporal_store(o0, (f32x4*)(crow + 0));
    __builtin_nontemporal_store(o1, (f32x4*)(crow + 4));
    return;
  }

  const int beg = (qtr == 0) ? 0 : (int)(qtr == 1 ? cq.x : qtr == 2 ? cq.y : cq.z);
  const int end = (int)(qtr == 0 ? cq.x : qtr == 1 ? cq.y : qtr == 2 ? cq.z : cq.w);

  if (qtr == 0) {
    a0 = a1 = a2 = a3 = a4 = a5 = a6 = a7 = 0.f;
  } else {
    f32x4 p0 = __builtin_nontemporal_load((const f32x4*)(crow + 0));
    f32x4 p1 = __builtin_nontemporal_load((const f32x4*)(crow + 4));
    a0 = p0.x; a1 = p0.y; a2 = p0.z; a3 = p0.w;
    a4 = p1.x; a5 = p1.y; a6 = p1.z; a7 = p1.w;
  }

  for (int g = beg; g < end; g += 8) {
    unsigned pk[8];
    #pragma unroll
    for (int k = 0; k < 8; ++k)
      pk[k] = (g + k < end) ? __builtin_nontemporal_load(rl + g + k) : 0u;
    u32x4 qv[8];                        // pad: f=0, v=0 -> gathers row 0, adds 0
    #pragma unroll
    for (int k = 0; k < 8; ++k)
      qv[k] = *(const u32x4*)(wtb + (size_t)(pk[k] & 8191u) * (NDIM * 2) + lane * 16);
    #pragma unroll
    for (int k = 0; k < 8; ++k) {
      float f = __uint_as_float(pk[k] & 0xFFFF0000u);
      FMA8(f, qv[k]);
    }
  }

  if (qtr == 3) {
    f32x4 o0 = {tanhf(a0), tanhf(a1), tanhf(a2), tanhf(a3)};
    f32x4 o1 = {tanhf(a4), tanhf(a5), tanhf(a6), tanhf(a7)};
    __builtin_nontemporal_store(o0, (f32x4*)(crow + 0));
    __builtin_nontemporal_store(o1, (f32x4*)(crow + 4));
  } else {
    f32x4 o0 = {a0, a1, a2, a3};
    f32x4 o1 = {a4, a5, a6, a7};
    __builtin_nontemporal_store(o0, (f32x4*)(crow + 0));
    __builtin_nontemporal_store(o1, (f32x4*)(crow + 4));
  }
#undef FMA8
}

// ---------------------------------------------------------------------------
extern "C" void kernel_launch(void* const* d_in, const int* in_sizes, int n_in,
                              void* d_out, int out_size, void* d_ws, size_t ws_size,
                              hipStream_t stream) {
  const float* x = (const float*)d_in[0];  // [8192, 8192] f32
  const float* W = (const float*)d_in[1];  // [512, 8192]  f32
  float* out = (float*)d_out;              // [8192, 512]  f32
  char* ws = (char*)d_ws;
  __bf16*   WT = (__bf16*)ws;
  unsigned* gl = (unsigned*)(ws + WS_GLIST);
  u32x4*    c4 = (u32x4*)(ws + WS_COUNT);

  transpose_w <<<dim3(1024),       dim3(256), 0, stream>>>(W, WT);
  scan_compact<<<dim3(M_ROWS / 4), dim3(256), 0, stream>>>(x, gl, c4);
  gather_qtr  <<<dim3(M_ROWS / 4), dim3(256), 0, stream>>>(x, WT, gl, c4, out, 0);
  gather_qtr  <<<dim3(M_ROWS / 4), dim3(256), 0, stream>>>(x, WT, gl, c4, out, 1);
  gather_qtr  <<<dim3(M_ROWS / 4), dim3(256), 0, stream>>>(x, WT, gl, c4, out, 2);
  gather_qtr  <<<dim3(M_ROWS / 4), dim3(256), 0, stream>>>(x, WT, gl, c4, out, 3);
}

// Round 13
// 96.368 us; speedup vs baseline: 1.3405x; 1.3405x over previous
//
#include <hip/hip_runtime.h>
#include <math.h>

#define M_ROWS 8192   // B*S
#define KDIM   8192   // V
#define NDIM   512    // D
#define CAP    512    // LDS pair slots per wave (mean nnz/row ~82, 47-sigma margin)

typedef float    f32x4  __attribute__((ext_vector_type(4)));
typedef unsigned u32x4  __attribute__((ext_vector_type(4)));
typedef __bf16   bf16x8 __attribute__((ext_vector_type(8)));

// ---------------------------------------------------------------------------
// Kernel 1: W [512, 8192] f32 -> WT [8192, 512] bf16 (d_ws, 8 MB).
__global__ __launch_bounds__(256)
void transpose_w(const float* __restrict__ W, __bf16* __restrict__ WT) {
  __shared__ float tile[64][65];
  const int t  = threadIdx.x;
  const int v0 = (blockIdx.x & 127) << 6;
  const int d0 = (blockIdx.x >> 7) << 6;
  #pragma unroll
  for (int i = 0; i < 4; ++i) {
    int idx = i * 256 + t;
    int r = idx >> 4;
    int c = (idx & 15) << 2;
    f32x4 val = __builtin_nontemporal_load(
        (const f32x4*)(W + (size_t)(d0 + r) * KDIM + v0 + c));
    tile[r][c + 0] = val.x; tile[r][c + 1] = val.y;
    tile[r][c + 2] = val.z; tile[r][c + 3] = val.w;
  }
  __syncthreads();
  #pragma unroll
  for (int i = 0; i < 2; ++i) {
    int idx = i * 256 + t;
    int vr = idx >> 3;
    int d8 = (idx & 7) << 3;
    bf16x8 u;
    #pragma unroll
    for (int j = 0; j < 8; ++j) u[j] = (__bf16)tile[d8 + j][vr];
    *(bf16x8*)(WT + (size_t)(v0 + vr) * NDIM + d0 + d8) = u;
  }
}

// ---------------------------------------------------------------------------
// Kernel 2: two-phase per wave (R6 configuration — measured 96.5 us).
//  Phase 1: stream row, ballot-compact nonzeros (fbits, v) into wave-private
//           LDS list — no gathers interleaved, scan loads pipeline freely.
//  Phase 2: drain list with 4-deep gather pipeline; pair reads are LDS
//           (lgkmcnt), so vmcnt waits count only gathers.
// Exact for any density; LDS overflow (never at ~1%) -> exact inline fallback.
__global__ __launch_bounds__(256)
void spmm_tanh(const float* __restrict__ A, const __bf16* __restrict__ WT,
               float* __restrict__ C) {
  __shared__ uint2 plist[4][CAP];   // 16 KB/block, wave-private slices
  const int lane = threadIdx.x & 63;
  const int w    = threadIdx.x >> 6;
  const int m    = blockIdx.x * 4 + w;
  const float* arow = A + (size_t)m * KDIM;
  const char*  wtb  = (const char*)WT;

  float a0 = 0.f, a1 = 0.f, a2 = 0.f, a3 = 0.f,
        a4 = 0.f, a5 = 0.f, a6 = 0.f, a7 = 0.f;

#define FMA8(f, q)                                                          \
  {                                                                         \
    a0 = fmaf(f, __uint_as_float((q).x << 16), a0);                         \
    a1 = fmaf(f, __uint_as_float((q).x & 0xffff0000u), a1);                 \
    a2 = fmaf(f, __uint_as_float((q).y << 16), a2);                         \
    a3 = fmaf(f, __uint_as_float((q).y & 0xffff0000u), a3);                 \
    a4 = fmaf(f, __uint_as_float((q).z << 16), a4);                         \
    a5 = fmaf(f, __uint_as_float((q).z & 0xffff0000u), a5);                 \
    a6 = fmaf(f, __uint_as_float((q).w << 16), a6);                         \
    a7 = fmaf(f, __uint_as_float((q).w & 0xffff0000u), a7);                 \
  }

  // ---- Phase 1: stream + compact
  int cur = 0;
  const unsigned long long ltmask = (lane == 63) ? ~0ull >> 1 : (1ull << lane) - 1;
  #pragma unroll 4
  for (int it = 0; it < KDIM / 256; ++it) {      // 32 iters x 1 KB/wave
    f32x4 av = __builtin_nontemporal_load((const f32x4*)(arow + it * 256 + lane * 4));
    #pragma unroll
    for (int j = 0; j < 4; ++j) {
      unsigned long long msk = __ballot(av[j] != 0.0f);
      if (msk == 0) continue;                     // ~53% of groups
      int cnt = __popcll(msk);
      if (cur + cnt <= CAP) {
        if (av[j] != 0.0f) {
          int pre = __popcll(msk & ltmask);
          plist[w][cur + pre] =
              make_uint2(__float_as_uint(av[j]),
                         (unsigned)(it * 256 + lane * 4 + j));
        }
        cur += cnt;
      } else {
        // exact overflow path (statistically never taken at ~1% density)
        while (msk) {
          int s = __builtin_ctzll(msk); msk &= msk - 1;
          float f = __shfl(av[j], s, 64);
          int v = it * 256 + s * 4 + j;
          u32x4 q = *(const u32x4*)(wtb + (size_t)v * (NDIM * 2) + lane * 16);
          FMA8(f, q);
        }
      }
    }
  }

  // ---- Phase 2: 4-deep static gather pipeline from the LDS list
  const int n = cur;
  if (n > 0) {
    const int ng = (n + 3) >> 2;
    // pair reader with branchless zero-padding past n
    auto rdp = [&](int i) -> uint2 {
      uint2 p = plist[w][i < CAP ? (i < n ? i : n - 1) : CAP - 1];
      if (i >= n) { p.x = 0u; p.y = 0u; }         // f=0 -> row-0 gather, adds 0
      return p;
    };
    uint2 p0 = rdp(0), p1 = rdp(1), p2 = rdp(2), p3 = rdp(3);
    for (int t = 0; t < ng; ++t) {
      const float    f0 = __uint_as_float(p0.x), f1 = __uint_as_float(p1.x);
      const float    f2 = __uint_as_float(p2.x), f3 = __uint_as_float(p3.x);
      const unsigned v0 = p0.y, v1 = p1.y, v2 = p2.y, v3 = p3.y;
      // 4 independent gathers in flight (vmcnt counts only these)
      u32x4 q0 = *(const u32x4*)(wtb + (size_t)v0 * (NDIM * 2) + lane * 16);
      u32x4 q1 = *(const u32x4*)(wtb + (size_t)v1 * (NDIM * 2) + lane * 16);
      u32x4 q2 = *(const u32x4*)(wtb + (size_t)v2 * (NDIM * 2) + lane * 16);
      u32x4 q3 = *(const u32x4*)(wtb + (size_t)v3 * (NDIM * 2) + lane * 16);
      // prefetch next pair group from LDS (lgkmcnt — doesn't drain gathers)
      if (t + 1 < ng) {
        int b = (t + 1) * 4;
        p0 = rdp(b); p1 = rdp(b + 1); p2 = rdp(b + 2); p3 = rdp(b + 3);
      }
      FMA8(f0, q0);
      FMA8(f1, q1);
      FMA8(f2, q2);
      FMA8(f3, q3);
    }
  }

  float* crow = C + (size_t)m * NDIM + lane * 8;
  f32x4 o0 = {tanhf(a0), tanhf(a1), tanhf(a2), tanhf(a3)};
  f32x4 o1 = {tanhf(a4), tanhf(a5), tanhf(a6), tanhf(a7)};
  __builtin_nontemporal_store(o0, (f32x4*)(crow + 0));
  __builtin_nontemporal_store(o1, (f32x4*)(crow + 4));
#undef FMA8
}

// ---------------------------------------------------------------------------
extern "C" void kernel_launch(void* const* d_in, const int* in_sizes, int n_in,
                              void* d_out, int out_size, void* d_ws, size_t ws_size,
                              hipStream_t stream) {
  const float* x = (const float*)d_in[0];  // [8192, 8192] f32
  const float* W = (const float*)d_in[1];  // [512, 8192]  f32
  float* out = (float*)d_out;              // [8192, 512]  f32
  __bf16* WT = (__bf16*)d_ws;              // [8192, 512]  bf16

  transpose_w<<<dim3(1024), dim3(256), 0, stream>>>(W, WT);
  spmm_tanh  <<<dim3(M_ROWS / 4), dim3(256), 0, stream>>>(x, WT, out);
}